// Round 6
// baseline (608.043 us; speedup 1.0000x reference)
//
#include <hip/hip_runtime.h>
#include <hip/hip_bf16.h>
#include <cstdint>
#include <cstddef>

#define C_CLS   100000
#define D_FEAT  512
#define B_ROWS  512
#define NBN     782          /* ceil(100000/128) */

#define COSM 0.8775825618903728f
#define SINM 0.479425538604203f
#define TH_  (-0.8775825618903728f)
#define MM_  0.2397127693021015f   /* sin(0.5)*0.5 */

typedef __bf16 bf16x8 __attribute__((ext_vector_type(8)));
typedef __bf16 bf16x4 __attribute__((ext_vector_type(4)));
typedef float  f32x4  __attribute__((ext_vector_type(4)));

// ---------------- kernel 1: normalize x rows -> bf16, zero accumulators ----
__global__ void k_xnorm(const float* __restrict__ x, __bf16* __restrict__ xn,
                        float* __restrict__ row_sum, float* __restrict__ tlogit) {
    const int row  = blockIdx.x;          // 512 blocks
    const int lane = threadIdx.x;         // 64 threads
    const f32x4* p = (const f32x4*)(x + (size_t)row * D_FEAT);
    f32x4 a = p[lane];
    f32x4 b = p[lane + 64];
    float s = a[0]*a[0] + a[1]*a[1] + a[2]*a[2] + a[3]*a[3]
            + b[0]*b[0] + b[1]*b[1] + b[2]*b[2] + b[3]*b[3];
    #pragma unroll
    for (int m = 32; m >= 1; m >>= 1) s += __shfl_xor(s, m, 64);
    const float inv = 1.0f / fmaxf(sqrtf(s), 1e-12f);
    bf16x4 o0 = { (__bf16)(a[0]*inv), (__bf16)(a[1]*inv), (__bf16)(a[2]*inv), (__bf16)(a[3]*inv) };
    bf16x4 o1 = { (__bf16)(b[0]*inv), (__bf16)(b[1]*inv), (__bf16)(b[2]*inv), (__bf16)(b[3]*inv) };
    *(bf16x4*)(xn + (size_t)row * D_FEAT + lane * 4)       = o0;
    *(bf16x4*)(xn + (size_t)row * D_FEAT + 256 + lane * 4) = o1;
    if (lane == 0) { row_sum[row] = 0.0f; tlogit[row] = 0.0f; }
}

// ------- kernel 2: normalize weight rows -> bf16 (fused norm + cast) ------
__global__ void k_wnorm(const float* __restrict__ w, __bf16* __restrict__ wn) {
    const int row  = blockIdx.x * 4 + (threadIdx.x >> 6);   // 25000 blocks x 4 rows
    const int lane = threadIdx.x & 63;
    if (row >= C_CLS) return;
    const f32x4* p = (const f32x4*)(w + (size_t)row * D_FEAT);
    f32x4 a = p[lane];
    f32x4 b = p[lane + 64];
    float s = a[0]*a[0] + a[1]*a[1] + a[2]*a[2] + a[3]*a[3]
            + b[0]*b[0] + b[1]*b[1] + b[2]*b[2] + b[3]*b[3];
    #pragma unroll
    for (int m = 32; m >= 1; m >>= 1) s += __shfl_xor(s, m, 64);
    const float inv = 1.0f / fmaxf(sqrtf(s), 1e-12f);
    bf16x4 o0 = { (__bf16)(a[0]*inv), (__bf16)(a[1]*inv), (__bf16)(a[2]*inv), (__bf16)(a[3]*inv) };
    bf16x4 o1 = { (__bf16)(b[0]*inv), (__bf16)(b[1]*inv), (__bf16)(b[2]*inv), (__bf16)(b[3]*inv) };
    *(bf16x4*)(wn + (size_t)row * D_FEAT + lane * 4)       = o0;
    *(bf16x4*)(wn + (size_t)row * D_FEAT + 256 + lane * 4) = o1;
}

// ---------------- kernel 3: persistent-A barrier-free MFMA GEMM -----------
// Each block: loads its 64x512 A-slice into LDS ONCE (swizzled, 64 KB, 2
// blocks/CU), then loops over bn tiles with NO barriers and NO LDS writes:
// B fragments stream global->VGPR with a depth-4 circular prefetch (16
// bf16x8 in flight covers L2/L3 latency), A fragments re-read from LDS
// (2-way bank aliasing = free). Rationale: R1/R2/R4/R5 all plateau at
// ~3000 cyc/block-iter regardless of staging mechanism -> 16-iter blocks
// never reach pipeline steady state; this removes the per-iter
// barrier/drain entirely.
__global__ __launch_bounds__(256, 2) void k_gemm(
        const __bf16* __restrict__ xn, const __bf16* __restrict__ wn,
        const int* __restrict__ y,
        float* __restrict__ row_sum, float* __restrict__ tlogit) {

    __shared__ __align__(16) __bf16 As[64 * 512];   // 64 KB, swizzled
    __shared__ int ys[64];

    const int tid = threadIdx.x;
    const int bm  = blockIdx.x & 7;        // 8 slices of 64 batch rows
    const int bn0 = blockIdx.x >> 3;       // 0..255

    const int wave = tid >> 6;
    const int lane = tid & 63;
    const int wm   = wave >> 1;            // 0..1 : 32-row half
    const int wn_  = wave & 1;             // 0..1 : 64-col half
    const int quad = lane >> 4;            // 0..3
    const int l15  = lane & 15;

    if (tid < 64) ys[tid] = y[bm * 64 + tid];

    // ---- one-time A-slice load: 4096 16B chunks, fully coalesced ----
    // chunk g -> row=g>>6, c=g&63; stored at row*512 + (c^(row&7))*8
    #pragma unroll
    for (int j = 0; j < 16; ++j) {
        const int g   = j * 256 + tid;
        const int row = g >> 6, c = g & 63;
        bf16x8 v = *(const bf16x8*)(xn + (size_t)(bm * 64 + row) * D_FEAT + c * 8);
        *(bf16x8*)&As[row * 512 + ((c ^ (row & 7)) * 8)] = v;
    }
    __syncthreads();   // the only barrier in the kernel

    for (int bn = bn0; bn < NBN; bn += 256) {
        // B fragment base pointers (16 class-rows per ni, clamped at tail)
        const __bf16* bp[4];
        #pragma unroll
        for (int ni = 0; ni < 4; ++ni) {
            int br = bn * 128 + wn_ * 64 + ni * 16 + l15;
            if (br > C_CLS - 1) br = C_CLS - 1;
            bp[ni] = wn + (size_t)br * D_FEAT + quad * 8;
        }
        // depth-4 circular prefetch: slots 0..3 = k-tiles kt..kt+3
        bf16x8 bq[4][4];
        #pragma unroll
        for (int p = 0; p < 4; ++p)
            #pragma unroll
            for (int ni = 0; ni < 4; ++ni)
                bq[p][ni] = *(const bf16x8*)(bp[ni] + p * 32);

        f32x4 acc[2][4];
        #pragma unroll
        for (int mi = 0; mi < 2; ++mi)
            #pragma unroll
            for (int ni = 0; ni < 4; ++ni) acc[mi][ni] = (f32x4){0.f, 0.f, 0.f, 0.f};

        #pragma unroll
        for (int kt = 0; kt < 16; ++kt) {
            const int sw = (((kt * 4 + quad) ^ (l15 & 7)) * 8);
            bf16x8 a0 = *(const bf16x8*)&As[(wm * 32 + l15) * 512 + sw];
            bf16x8 a1 = *(const bf16x8*)&As[(wm * 32 + 16 + l15) * 512 + sw];
            bf16x8 b0 = bq[kt & 3][0];
            bf16x8 b1 = bq[kt & 3][1];
            bf16x8 b2 = bq[kt & 3][2];
            bf16x8 b3 = bq[kt & 3][3];
            if (kt < 12) {     // refill slot with k-tile kt+4
                #pragma unroll
                for (int ni = 0; ni < 4; ++ni)
                    bq[kt & 3][ni] = *(const bf16x8*)(bp[ni] + (kt + 4) * 32);
            }
            acc[0][0] = __builtin_amdgcn_mfma_f32_16x16x32_bf16(a0, b0, acc[0][0], 0, 0, 0);
            acc[0][1] = __builtin_amdgcn_mfma_f32_16x16x32_bf16(a0, b1, acc[0][1], 0, 0, 0);
            acc[0][2] = __builtin_amdgcn_mfma_f32_16x16x32_bf16(a0, b2, acc[0][2], 0, 0, 0);
            acc[0][3] = __builtin_amdgcn_mfma_f32_16x16x32_bf16(a0, b3, acc[0][3], 0, 0, 0);
            acc[1][0] = __builtin_amdgcn_mfma_f32_16x16x32_bf16(a1, b0, acc[1][0], 0, 0, 0);
            acc[1][1] = __builtin_amdgcn_mfma_f32_16x16x32_bf16(a1, b1, acc[1][1], 0, 0, 0);
            acc[1][2] = __builtin_amdgcn_mfma_f32_16x16x32_bf16(a1, b2, acc[1][2], 0, 0, 0);
            acc[1][3] = __builtin_amdgcn_mfma_f32_16x16x32_bf16(a1, b3, acc[1][3], 0, 0, 0);
        }

        // ---- per-tile epilogue: cos -> margin -> exp(logit-64) -> sums ----
        #pragma unroll
        for (int mi = 0; mi < 2; ++mi) {
            float rs[4] = {0.f, 0.f, 0.f, 0.f};
            #pragma unroll
            for (int ni = 0; ni < 4; ++ni) {
                const int gcol = bn * 128 + wn_ * 64 + ni * 16 + l15;
                const bool colv = (gcol < C_CLS);
                #pragma unroll
                for (int reg = 0; reg < 4; ++reg) {
                    const int lrow = wm * 32 + mi * 16 + quad * 4 + reg;
                    const float cosv = acc[mi][ni][reg];
                    const float sinv = sqrtf(fmaxf(1.0f - cosv * cosv, 0.0f));
                    const float phi  = (cosv > TH_) ? (cosv * COSM - sinv * SINM) : (cosv - MM_);
                    const bool ist   = colv && (gcol == ys[lrow]);
                    const float logit = 64.0f * (ist ? phi : cosv);
                    if (ist) tlogit[bm * 64 + lrow] = logit;
                    rs[reg] += colv ? __expf(logit - 64.0f) : 0.0f;
                }
            }
            #pragma unroll
            for (int reg = 0; reg < 4; ++reg) {
                float v = rs[reg];
                v += __shfl_xor(v, 8, 64);
                v += __shfl_xor(v, 4, 64);
                v += __shfl_xor(v, 2, 64);
                v += __shfl_xor(v, 1, 64);
                if (l15 == 0) {
                    const int lrow = wm * 32 + mi * 16 + quad * 4 + reg;
                    atomicAdd(&row_sum[bm * 64 + lrow], v);
                }
            }
        }
    }
}

// ---------------- kernel 4: finalize loss ---------------------------------
__global__ void k_final(const float* __restrict__ row_sum, const float* __restrict__ tlogit,
                        float* __restrict__ out) {
    const int t = threadIdx.x;     // 512 threads
    float v = logf(row_sum[t]) + 64.0f - tlogit[t];
    #pragma unroll
    for (int m = 32; m >= 1; m >>= 1) v += __shfl_xor(v, m, 64);
    __shared__ float partial[8];
    if ((t & 63) == 0) partial[t >> 6] = v;
    __syncthreads();
    if (t == 0) {
        float s = 0.f;
        #pragma unroll
        for (int i = 0; i < 8; ++i) s += partial[i];
        out[0] = s * (1.0f / 512.0f);
    }
}

extern "C" void kernel_launch(void* const* d_in, const int* in_sizes, int n_in,
                              void* d_out, int out_size, void* d_ws, size_t ws_size,
                              hipStream_t stream) {
    const float* x = (const float*)d_in[0];
    const int*   y = (const int*)d_in[1];
    const float* w = (const float*)d_in[2];

    char* ws = (char*)d_ws;
    __bf16* xn      = (__bf16*)ws;                                  // 524288 B
    __bf16* wnorm   = (__bf16*)(ws + 524288);                       // 102400000 B
    float*  row_sum = (float*)(ws + 524288 + 102400000);            // 2048 B
    float*  tlogit  = (float*)(ws + 524288 + 102400000 + 2048);     // 2048 B
    float*  out     = (float*)d_out;

    hipLaunchKernelGGL(k_xnorm, dim3(512), dim3(64), 0, stream, x, xn, row_sum, tlogit);
    hipLaunchKernelGGL(k_wnorm, dim3(25000), dim3(256), 0, stream, w, wnorm);
    hipLaunchKernelGGL(k_gemm, dim3(2048), dim3(256), 0, stream, xn, wnorm, y, row_sum, tlogit);
    hipLaunchKernelGGL(k_final, dim3(1), dim3(512), 0, stream, row_sum, tlogit, out);
}